// Round 4
// baseline (370.073 us; speedup 1.0000x reference)
//
#include <hip/hip_runtime.h>
#include <hip/hip_bf16.h>

typedef __bf16 bf16_t;
typedef __attribute__((ext_vector_type(8))) __bf16 bf16x8;
typedef __attribute__((ext_vector_type(4))) __bf16 bf16x4;
typedef __attribute__((ext_vector_type(4))) float f32x4;

#define NPOS 38416  // 196*196
#define NPAD 224    // 7*32
#define KSTR 40     // kf row stride (bf16): 80B = 20 banks -> 2-way (free)
#define VSTR 232    // vts/pb row stride (bf16): 464B, 16B-aligned, 2-way

__device__ __forceinline__ void async_copy16(const bf16_t* g, bf16_t* l) {
  __builtin_amdgcn_global_load_lds((const __attribute__((address_space(1))) void*)g,
                                   (__attribute__((address_space(3))) void*)l, 16, 0, 0);
}

// ---------------- cast x -> bf16 ----------------
__global__ __launch_bounds__(256) void cast_x_kernel(const float* __restrict__ x,
                                                     bf16_t* __restrict__ xb, int n4) {
  int i = blockIdx.x * 256 + threadIdx.x;
  if (i < n4) {
    float4 v = ((const float4*)x)[i];
    bf16x4 o;
    o[0] = (bf16_t)v.x; o[1] = (bf16_t)v.y; o[2] = (bf16_t)v.z; o[3] = (bf16_t)v.w;
    ((bf16x4*)xb)[i] = o;
  }
}

// ---------------- transpose + cast W: src[K][Ncols] f32 -> dst[Ncols][K] bf16 ----------------
__global__ __launch_bounds__(256) void transpose_cast_kernel(const float* __restrict__ src,
                                                             bf16_t* __restrict__ dst,
                                                             int K, int Ncols) {
  __shared__ float tile[32][33];
  int t = threadIdx.x;
  int tx = t & 31, ty = t >> 5;
  int bx = blockIdx.x, by = blockIdx.y;
  for (int r = ty; r < 32; r += 8)
    tile[r][tx] = src[(size_t)(by * 32 + r) * Ncols + bx * 32 + tx];
  __syncthreads();
  for (int r = ty; r < 32; r += 8)
    dst[(size_t)(bx * 32 + r) * K + by * 32 + tx] = (bf16_t)tile[tx][r];
}

// ---------------- bias gather: bias[h][i*196+j] = rpk[rel_idx[i][j]][h] ----------------
__global__ __launch_bounds__(256) void bias_gather_kernel(const float* __restrict__ rpk,
                                                          const int* __restrict__ rel_idx,
                                                          float* __restrict__ bias) {
  int pos = blockIdx.x * 256 + threadIdx.x;
  if (pos < NPOS) {
    int idx = rel_idx[pos];
    const float* r = rpk + idx * 32;
#pragma unroll
    for (int h = 0; h < 32; ++h) bias[h * NPOS + pos] = r[h];
  }
}

// ---------------- 128x128 bf16 GEMM, B^T input, K=1024 (m97 structure) ----------------
// Guide-measured tile-space at this 2-barrier structure: 128^2 = 912 TF beats
// 128x256 = 823 and 256^2 = 792 (m92/m103/m105/m112).  256 threads / 4 waves
// (2x2 of 64x64).  Double-buffered LDS (32 KiB -> 4 blocks/CU; cross-block
// overlap hides the barrier drain), ONE barrier per K-iter: loads for tile
// k+1 issue right after the barrier and land during tile-k compute.  16B-chunk
// XOR swizzle (phys_chunk = glob_chunk ^ ((row>>1)&3); rows are multiples of
// 16 at the fragment read, so qa = quad ^ ((l16>>1)&3) is unchanged).
// Retile rationale: more blocks (gemm1 1176->2352, gemm2 392->784) => more
// co-resident blocks/CU => more cross-block latency hiding (the mechanism
// this structure relies on); gemm2's old 392-block launch was a half-empty
// machine (~0.5 fills) running at one block's full latency.
// XCD-chunked bijective block swizzle kept (FETCH -22% measured; both new
// grids divide by 8 exactly: 2352 = 8*294, 784 = 8*98).
template <int MODE>
__global__ __launch_bounds__(256, 4) void gemm_bt_kernel(
    const bf16_t* __restrict__ A, const bf16_t* __restrict__ Bt,
    bf16_t* __restrict__ qo, bf16_t* __restrict__ ko, bf16_t* __restrict__ vto,
    float* __restrict__ fo, const float* __restrict__ bp) {
  constexpr int K = 1024;
  constexpr int CH = 256 * 32;  // bf16 elems per buffer: (128 A-rows + 128 B-rows) x 32
  __shared__ alignas(16) bf16_t S[2][CH];
  const int t = threadIdx.x;
  const int lane = t & 63;
  const int quad = lane >> 4;
  const int l16 = lane & 15;
  const int wave = t >> 6;

  // T1: bijective XCD-chunked swizzle (m204). Consecutive linear block ids
  // round-robin across the 8 XCDs; give each XCD a contiguous chunk instead.
  const int GX = gridDim.x;
  const int nwg = GX * gridDim.y;
  const int lin = blockIdx.y * GX + blockIdx.x;
  const int qch = nwg >> 3, rch = nwg & 7;
  const int xcd = lin & 7, off = lin >> 3;
  const int swz = (xcd < rch ? xcd * (qch + 1) : rch * (qch + 1) + (xcd - rch) * qch) + off;
  const int m0 = (swz / GX) * 128, n0 = (swz % GX) * 128;

  const int wr = (wave >> 1) * 64, wc = (wave & 1) * 64;

  // staging: 1024 16B-chunks; thread t covers c = t, t+256, t+512, t+768
  const bf16_t* gp[4];
  int lofs[4];
#pragma unroll
  for (int j = 0; j < 4; ++j) {
    const int c = t + j * 256;
    const int row = c >> 2;
    const int sc = (c & 3) ^ ((c >> 3) & 3);
    gp[j] = (row < 128) ? A + (size_t)(m0 + row) * K + sc * 8
                        : Bt + (size_t)(n0 + row - 128) * K + sc * 8;
    lofs[j] = c * 8;
  }

  // fragment reads: global chunk `quad` lives at phys chunk quad ^ ((l16>>1)&3)
  const int qa = quad ^ ((l16 >> 1) & 3);

  const f32x4 vzero = {0.f, 0.f, 0.f, 0.f};
  f32x4 acc[4][4];
#pragma unroll
  for (int i = 0; i < 4; ++i)
#pragma unroll
    for (int j = 0; j < 4; ++j) acc[i][j] = vzero;

  // preload k-tile 0 into S[0]
#pragma unroll
  for (int j = 0; j < 4; ++j) async_copy16(gp[j], &S[0][lofs[j]]);

  for (int it = 0; it < K / 32; ++it) {
    __syncthreads();  // drains loads issued one full iteration ago
    const bf16_t* Sb = S[it & 1];
    if (it + 1 < K / 32) {
      bf16_t* Sn = S[(it + 1) & 1];
      const int kt = (it + 1) * 32;
#pragma unroll
      for (int j = 0; j < 4; ++j) async_copy16(gp[j] + kt, Sn + lofs[j]);
    }
    const bf16_t* As = Sb;
    const bf16_t* Bs = Sb + 128 * 32;
    bf16x8 af[4], bfr[4];
#pragma unroll
    for (int i = 0; i < 4; ++i) {
      af[i] = *(const bf16x8*)(As + (wr + i * 16 + l16) * 32 + qa * 8);
      bfr[i] = *(const bf16x8*)(Bs + (wc + i * 16 + l16) * 32 + qa * 8);
    }
#pragma unroll
    for (int i = 0; i < 4; ++i)
#pragma unroll
      for (int j = 0; j < 4; ++j)
        acc[i][j] = __builtin_amdgcn_mfma_f32_16x16x32_bf16(af[i], bfr[j], acc[i][j], 0, 0, 0);
  }

  if (MODE == 0) {
    const float qscale = 0.17677669529663687f;  // 1/sqrt(32)
    const int which = n0 >> 10;                 // uniform per block (1024 % 128 == 0)
#pragma unroll
    for (int i = 0; i < 4; ++i) {
      const int rb = m0 + wr + i * 16 + quad * 4;
#pragma unroll
      for (int j = 0; j < 4; ++j) {
        const int c = n0 + wc + j * 16 + l16;
        const int h = (c >> 5) & 31, d = c & 31;
#pragma unroll
        for (int r = 0; r < 4; ++r) {
          const int rg = rb + r;
          const int b = rg / 196, n = rg - b * 196;
          const float v = acc[i][j][r];
          if (which == 0)
            qo[(((size_t)b * 32 + h) * 196 + n) * 32 + d] = (bf16_t)(v * qscale);
          else if (which == 1)
            ko[(((size_t)b * 32 + h) * 196 + n) * 32 + d] = (bf16_t)v;
          else
            vto[(((size_t)b * 32 + h) * 32 + d) * 196 + n] = (bf16_t)v;
        }
      }
    }
  } else {
#pragma unroll
    for (int i = 0; i < 4; ++i) {
      const int rb = m0 + wr + i * 16 + quad * 4;
#pragma unroll
      for (int j = 0; j < 4; ++j) {
        const int c = n0 + wc + j * 16 + l16;
        const float bias_c = bp[c];
#pragma unroll
        for (int r = 0; r < 4; ++r)
          fo[(size_t)(rb + r) * 1024 + c] = acc[i][j][r] + bias_c;
      }
    }
  }
}

// ---------------- attention: one block per (b,h); wave-private, barrier-free main loop ----------------
__global__ __launch_bounds__(256, 2) void attn_kernel(
    const bf16_t* __restrict__ q, const bf16_t* __restrict__ kmat,
    const bf16_t* __restrict__ vtg, const float* __restrict__ bias,
    bf16_t* __restrict__ attn_out) {
  __shared__ alignas(16) bf16_t kf[NPAD * KSTR];    // K rows [n][d], stride 40
  __shared__ alignas(16) bf16_t vts[32 * VSTR];     // V^T [d][n], stride 232
  __shared__ alignas(16) bf16_t pb[4][16 * VSTR];   // per-wave unnormalized P

  const int t = threadIdx.x;
  const int lane = t & 63;
  const int quad = lane >> 4, l16 = lane & 15;
  const int wave = t >> 6;
  const int bh = blockIdx.x;
  const int b = bh >> 5, h = bh & 31;
  const bf16_t* qg = q + (size_t)bh * (196 * 32);
  const bf16_t* kg = kmat + (size_t)bh * (196 * 32);
  const bf16_t* vg = vtg + (size_t)bh * (32 * 196);
  const float* bg = bias + (size_t)h * NPOS;

  {
    const uint4* src = (const uint4*)kg;
    uint4* dst = (uint4*)kf;  // row r -> uint4 slots [r*5, r*5+3]; slot r*5+4 unused
    for (int c = t; c < 784; c += 256) dst[(c >> 2) * 5 + (c & 3)] = src[c];
    const uint4 z4 = {0u, 0u, 0u, 0u};
    if (t < 112) {  // zero pad rows 196..223, chunks 0..3
      int r = 196 + (t >> 2), ch = t & 3;
      dst[r * 5 + ch] = z4;
    }
    const uint2 z2 = {0u, 0u};
    for (int i = t; i < 1792; i += 256) {  // 32 rows x 56 x 8B (stride VSTR)
      int d = i / 56, c = i - d * 56;
      uint2 val = (c < 49) ? ((const uint2*)(vg + d * 196))[c] : z2;
      ((uint2*)(vts + d * VSTR))[c] = val;
    }
  }
  __syncthreads();

  const f32x4 vzero = {0.f, 0.f, 0.f, 0.f};
  bf16_t* pw = &pb[wave][0];

  for (int ch = wave; ch < 13; ch += 4) {
    const int q0 = ch * 16;
    int qrow = q0 + l16;
    if (qrow > 195) qrow = 195;  // clamp; junk rows never stored
    const bf16x8 aq = *(const bf16x8*)(qg + qrow * 32 + quad * 8);

    // prefetch bias into registers (independent of the MFMAs below)
    float bv[13][4];
#pragma unroll
    for (int ct = 0; ct < 13; ++ct) {
      const int col = ct * 16 + l16;
#pragma unroll
      for (int r = 0; r < 4; ++r) {
        int br = q0 + quad * 4 + r;
        if (br > 195) br = 195;
        bv[ct][r] = (col < 196) ? bg[br * 196 + col] : 0.f;
      }
    }

    f32x4 s[13];
#pragma unroll
    for (int ct = 0; ct < 13; ++ct) {
      const bf16x8 bk = *(const bf16x8*)(kf + (ct * 16 + l16) * KSTR + quad * 8);
      s[ct] = __builtin_amdgcn_mfma_f32_16x16x32_bf16(aq, bk, vzero, 0, 0, 0);
    }
#pragma unroll
    for (int ct = 0; ct < 13; ++ct) {
      const int col = ct * 16 + l16;
#pragma unroll
      for (int r = 0; r < 4; ++r) {
        if (col < 196)
          s[ct][r] += bv[ct][r];
        else
          s[ct][r] = -1e30f;
      }
    }
    // row max (cols of one row live in the 16-lane group)
    float mx[4], inv[4];
#pragma unroll
    for (int r = 0; r < 4; ++r) {
      float m = s[0][r];
#pragma unroll
      for (int ct = 1; ct < 13; ++ct) m = fmaxf(m, s[ct][r]);
      m = fmaxf(m, __shfl_xor(m, 1));
      m = fmaxf(m, __shfl_xor(m, 2));
      m = fmaxf(m, __shfl_xor(m, 4));
      m = fmaxf(m, __shfl_xor(m, 8));
      mx[r] = m;
    }
#pragma unroll
    for (int ct = 0; ct < 13; ++ct)
#pragma unroll
      for (int r = 0; r < 4; ++r) s[ct][r] = __expf(s[ct][r] - mx[r]);  // masked -> 0
#pragma unroll
    for (int r = 0; r < 4; ++r) {
      float sum = s[0][r];
#pragma unroll
      for (int ct = 1; ct < 13; ++ct) sum += s[ct][r];
      sum += __shfl_xor(sum, 1);
      sum += __shfl_xor(sum, 2);
      sum += __shfl_xor(sum, 4);
      sum += __shfl_xor(sum, 8);
      inv[r] = 1.f / sum;
    }
    // P -> wave-private LDS (C layout -> memory [row][col])
#pragma unroll
    for (int ct = 0; ct < 13; ++ct) {
      const int col = ct * 16 + l16;
#pragma unroll
      for (int r = 0; r < 4; ++r) pw[(quad * 4 + r) * VSTR + col] = (bf16_t)s[ct][r];
    }
    // zero pad tile (cols 208..223)
    if (lane < 32) {
      const bf16x8 z8 = {};
      *(bf16x8*)(pw + (lane >> 1) * VSTR + 208 + (lane & 1) * 8) = z8;
    }
    // PV: same-wave LDS read-back (A layout), no barrier needed
#pragma unroll
    for (int dt = 0; dt < 2; ++dt) {
      f32x4 o = vzero;
#pragma unroll
      for (int kk = 0; kk < 7; ++kk) {
        const bf16x8 ap = *(const bf16x8*)(pw + l16 * VSTR + kk * 32 + quad * 8);
        const bf16x8 bv2 = *(const bf16x8*)(vts + (dt * 16 + l16) * VSTR + kk * 32 + quad * 8);
        o = __builtin_amdgcn_mfma_f32_16x16x32_bf16(ap, bv2, o, 0, 0, 0);
      }
      const int d = dt * 16 + l16;
#pragma unroll
      for (int r = 0; r < 4; ++r) {
        const int n = q0 + quad * 4 + r;
        if (n < 196)
          attn_out[(((size_t)b * 196 + n) * 32 + h) * 32 + d] = (bf16_t)(o[r] * inv[r]);
      }
    }
  }
}

extern "C" void kernel_launch(void* const* d_in, const int* in_sizes, int n_in,
                              void* d_out, int out_size, void* d_ws, size_t ws_size,
                              hipStream_t stream) {
  (void)in_sizes; (void)n_in; (void)out_size; (void)ws_size;
  const float* x = (const float*)d_in[0];
  const float* Wqkv = (const float*)d_in[1];
  const float* Wproj = (const float*)d_in[2];
  const float* bproj = (const float*)d_in[3];
  const float* rpk = (const float*)d_in[4];
  const int* rel_idx = (const int*)d_in[5];
  float* out = (float*)d_out;

  char* ws = (char*)d_ws;
  bf16_t* xb = (bf16_t*)(ws + 0);                  // 25,690,112 B ; reused as attn_out
  bf16_t* wqkvT = (bf16_t*)(ws + 25690112);        //  6,291,456 B
  bf16_t* wprojT = (bf16_t*)(ws + 31981568);       //  2,097,152 B
  bf16_t* q = (bf16_t*)(ws + 34078720);            // 25,690,112 B
  bf16_t* kk = (bf16_t*)(ws + 59768832);           // 25,690,112 B
  bf16_t* vt = (bf16_t*)(ws + 85458944);           // 25,690,112 B
  float* bias = (float*)(ws + 111149056);          //  4,917,248 B  (total ~116 MB)
  bf16_t* attn = xb;                               // xb is dead after GEMM1

  cast_x_kernel<<<12544, 256, 0, stream>>>(x, xb, 12845056 / 4);
  transpose_cast_kernel<<<dim3(96, 32), 256, 0, stream>>>(Wqkv, wqkvT, 1024, 3072);
  transpose_cast_kernel<<<dim3(32, 32), 256, 0, stream>>>(Wproj, wprojT, 1024, 1024);
  bias_gather_kernel<<<151, 256, 0, stream>>>(rpk, rel_idx, bias);
  gemm_bt_kernel<0><<<dim3(24, 98), 256, 0, stream>>>(xb, wqkvT, q, kk, vt, nullptr, nullptr);
  attn_kernel<<<2048, 256, 0, stream>>>(q, kk, vt, bias, attn);
  gemm_bt_kernel<1><<<dim3(8, 98), 256, 0, stream>>>(attn, wprojT, nullptr, nullptr, nullptr, out, bproj);
}

// Round 7
// 344.991 us; speedup vs baseline: 1.0727x; 1.0727x over previous
//
#include <hip/hip_runtime.h>
#include <hip/hip_bf16.h>

typedef __bf16 bf16_t;
typedef __attribute__((ext_vector_type(8))) __bf16 bf16x8;
typedef __attribute__((ext_vector_type(4))) __bf16 bf16x4;
typedef __attribute__((ext_vector_type(4))) float f32x4;

#define NPOS 38416  // 196*196
#define NPAD 224    // 7*32
#define KSTR 40     // kf row stride (bf16): 80B = 20 banks -> 2-way (free)
#define VSTR 232    // vts/pb row stride (bf16): 464B, 16B-aligned, 2-way

__device__ __forceinline__ void async_copy16(const bf16_t* g, bf16_t* l) {
  __builtin_amdgcn_global_load_lds((const __attribute__((address_space(1))) void*)g,
                                   (__attribute__((address_space(3))) void*)l, 16, 0, 0);
}

// ---------------- cast x -> bf16 ----------------
__global__ __launch_bounds__(256) void cast_x_kernel(const float* __restrict__ x,
                                                     bf16_t* __restrict__ xb, int n4) {
  int i = blockIdx.x * 256 + threadIdx.x;
  if (i < n4) {
    float4 v = ((const float4*)x)[i];
    bf16x4 o;
    o[0] = (bf16_t)v.x; o[1] = (bf16_t)v.y; o[2] = (bf16_t)v.z; o[3] = (bf16_t)v.w;
    ((bf16x4*)xb)[i] = o;
  }
}

// ---------------- transpose + cast W: src[K][Ncols] f32 -> dst[Ncols][K] bf16 ----------------
__global__ __launch_bounds__(256) void transpose_cast_kernel(const float* __restrict__ src,
                                                             bf16_t* __restrict__ dst,
                                                             int K, int Ncols) {
  __shared__ float tile[32][33];
  int t = threadIdx.x;
  int tx = t & 31, ty = t >> 5;
  int bx = blockIdx.x, by = blockIdx.y;
  for (int r = ty; r < 32; r += 8)
    tile[r][tx] = src[(size_t)(by * 32 + r) * Ncols + bx * 32 + tx];
  __syncthreads();
  for (int r = ty; r < 32; r += 8)
    dst[(size_t)(bx * 32 + r) * K + by * 32 + tx] = (bf16_t)tile[tx][r];
}

// ---------------- bias gather: bias[h][i*196+j] = rpk[rel_idx[i][j]][h] ----------------
__global__ __launch_bounds__(256) void bias_gather_kernel(const float* __restrict__ rpk,
                                                          const int* __restrict__ rel_idx,
                                                          float* __restrict__ bias) {
  int pos = blockIdx.x * 256 + threadIdx.x;
  if (pos < NPOS) {
    int idx = rel_idx[pos];
    const float* r = rpk + idx * 32;
#pragma unroll
    for (int h = 0; h < 32; ++h) bias[h * NPOS + pos] = r[h];
  }
}

// ---------------- 256x128 bf16 GEMM, B^T input, K=1024 ----------------
// PROVEN round-3 structure (119.8 us gemm1, 342.9 total): 512 threads /
// 8 waves (4x2 of 64x64). Double-buffered LDS (48 KiB -> 3 blocks/CU;
// cross-block overlap hides the barrier drain), ONE barrier per K-iter.
// 16B-chunk XOR swizzle (phys_chunk = glob_chunk ^ ((row>>1)&3)).
// Bijective XCD-chunked block swizzle (FETCH -22% measured, time-neutral,
// kept for headroom).  Do NOT retile to 128^2: measured r4, FETCH doubles
// (91->174 MB) and gemm1 +13 us on this tall-skinny shape.
template <int MODE>
__global__ __launch_bounds__(512, 4) void gemm_bt_kernel(
    const bf16_t* __restrict__ A, const bf16_t* __restrict__ Bt,
    bf16_t* __restrict__ qo, bf16_t* __restrict__ ko, bf16_t* __restrict__ vto,
    float* __restrict__ fo, const float* __restrict__ bp) {
  constexpr int K = 1024;
  constexpr int CH = 384 * 32;  // bf16 elems per buffer: (256 A-rows + 128 B-rows) x 32
  __shared__ alignas(16) bf16_t S[2][CH];
  const int t = threadIdx.x;
  const int lane = t & 63;
  const int quad = lane >> 4;
  const int l16 = lane & 15;
  const int wave = t >> 6;

  // T1: bijective XCD-chunked swizzle (m204)
  const int GX = gridDim.x;
  const int nwg = GX * gridDim.y;
  const int lin = blockIdx.y * GX + blockIdx.x;
  const int qch = nwg >> 3, rch = nwg & 7;
  const int xcd = lin & 7, off = lin >> 3;
  const int swz = (xcd < rch ? xcd * (qch + 1) : rch * (qch + 1) + (xcd - rch) * qch) + off;
  const int m0 = (swz / GX) * 256, n0 = (swz % GX) * 128;

  const int wr = (wave >> 1) * 64, wc = (wave & 1) * 64;

  // staging: 1536 16B-chunks; thread t covers c = t, t+512, t+1024
  const bf16_t* gp[3];
  int lofs[3];
#pragma unroll
  for (int j = 0; j < 3; ++j) {
    const int c = t + j * 512;
    const int row = c >> 2;
    const int sc = (c & 3) ^ ((c >> 3) & 3);
    gp[j] = (row < 256) ? A + (size_t)(m0 + row) * K + sc * 8
                        : Bt + (size_t)(n0 + row - 256) * K + sc * 8;
    lofs[j] = c * 8;
  }

  // fragment reads: global chunk `quad` lives at phys chunk quad ^ ((l16>>1)&3)
  const int qa = quad ^ ((l16 >> 1) & 3);

  const f32x4 vzero = {0.f, 0.f, 0.f, 0.f};
  f32x4 acc[4][4];
#pragma unroll
  for (int i = 0; i < 4; ++i)
#pragma unroll
    for (int j = 0; j < 4; ++j) acc[i][j] = vzero;

  // preload k-tile 0 into S[0]
#pragma unroll
  for (int j = 0; j < 3; ++j) async_copy16(gp[j], &S[0][lofs[j]]);

  for (int it = 0; it < K / 32; ++it) {
    __syncthreads();  // drains loads issued one full iteration ago
    const bf16_t* Sb = S[it & 1];
    if (it + 1 < K / 32) {
      bf16_t* Sn = S[(it + 1) & 1];
      const int kt = (it + 1) * 32;
#pragma unroll
      for (int j = 0; j < 3; ++j) async_copy16(gp[j] + kt, Sn + lofs[j]);
    }
    const bf16_t* As = Sb;
    const bf16_t* Bs = Sb + 256 * 32;
    bf16x8 af[4], bfr[4];
#pragma unroll
    for (int i = 0; i < 4; ++i) {
      af[i] = *(const bf16x8*)(As + (wr + i * 16 + l16) * 32 + qa * 8);
      bfr[i] = *(const bf16x8*)(Bs + (wc + i * 16 + l16) * 32 + qa * 8);
    }
#pragma unroll
    for (int i = 0; i < 4; ++i)
#pragma unroll
      for (int j = 0; j < 4; ++j)
        acc[i][j] = __builtin_amdgcn_mfma_f32_16x16x32_bf16(af[i], bfr[j], acc[i][j], 0, 0, 0);
  }

  if (MODE == 0) {
    const float qscale = 0.17677669529663687f;  // 1/sqrt(32)
    const int which = n0 >> 10;                 // uniform per block (1024 % 128 == 0)
#pragma unroll
    for (int i = 0; i < 4; ++i) {
      const int rb = m0 + wr + i * 16 + quad * 4;
#pragma unroll
      for (int j = 0; j < 4; ++j) {
        const int c = n0 + wc + j * 16 + l16;
        const int h = (c >> 5) & 31, d = c & 31;
#pragma unroll
        for (int r = 0; r < 4; ++r) {
          const int rg = rb + r;
          const int b = rg / 196, n = rg - b * 196;
          const float v = acc[i][j][r];
          if (which == 0)
            qo[(((size_t)b * 32 + h) * 196 + n) * 32 + d] = (bf16_t)(v * qscale);
          else if (which == 1)
            ko[(((size_t)b * 32 + h) * 196 + n) * 32 + d] = (bf16_t)v;
          else
            vto[(((size_t)b * 32 + h) * 32 + d) * 196 + n] = (bf16_t)v;
        }
      }
    }
  } else {
#pragma unroll
    for (int i = 0; i < 4; ++i) {
      const int rb = m0 + wr + i * 16 + quad * 4;
#pragma unroll
      for (int j = 0; j < 4; ++j) {
        const int c = n0 + wc + j * 16 + l16;
        const float bias_c = bp[c];
#pragma unroll
        for (int r = 0; r < 4; ++r)
          fo[(size_t)(rb + r) * 1024 + c] = acc[i][j][r] + bias_c;
      }
    }
  }
}

// ---------------- attention: one block per (b,h); wave-private, barrier-free main loop ----------------
// h-MAJOR block order (ONLY change vs round-3): consecutive blocks share the
// same head h, so each XCD's resident block window spans ~8 bias planes
// (1.2 MB, L2-resident) instead of all 32 (4.9 MB > 4 MB per-XCD L2).
__global__ __launch_bounds__(256, 2) void attn_kernel(
    const bf16_t* __restrict__ q, const bf16_t* __restrict__ kmat,
    const bf16_t* __restrict__ vtg, const float* __restrict__ bias,
    bf16_t* __restrict__ attn_out) {
  __shared__ alignas(16) bf16_t kf[NPAD * KSTR];    // K rows [n][d], stride 40
  __shared__ alignas(16) bf16_t vts[32 * VSTR];     // V^T [d][n], stride 232
  __shared__ alignas(16) bf16_t pb[4][16 * VSTR];   // per-wave unnormalized P

  const int t = threadIdx.x;
  const int lane = t & 63;
  const int quad = lane >> 4, l16 = lane & 15;
  const int wave = t >> 6;
  const int b = blockIdx.x & 63, h = blockIdx.x >> 6;  // h-major decode
  const int bh = b * 32 + h;                           // memory layout index
  const bf16_t* qg = q + (size_t)bh * (196 * 32);
  const bf16_t* kg = kmat + (size_t)bh * (196 * 32);
  const bf16_t* vg = vtg + (size_t)bh * (32 * 196);
  const float* bg = bias + (size_t)h * NPOS;

  {
    const uint4* src = (const uint4*)kg;
    uint4* dst = (uint4*)kf;  // row r -> uint4 slots [r*5, r*5+3]; slot r*5+4 unused
    for (int c = t; c < 784; c += 256) dst[(c >> 2) * 5 + (c & 3)] = src[c];
    const uint4 z4 = {0u, 0u, 0u, 0u};
    if (t < 112) {  // zero pad rows 196..223, chunks 0..3
      int r = 196 + (t >> 2), ch = t & 3;
      dst[r * 5 + ch] = z4;
    }
    const uint2 z2 = {0u, 0u};
    for (int i = t; i < 1792; i += 256) {  // 32 rows x 56 x 8B (stride VSTR)
      int d = i / 56, c = i - d * 56;
      uint2 val = (c < 49) ? ((const uint2*)(vg + d * 196))[c] : z2;
      ((uint2*)(vts + d * VSTR))[c] = val;
    }
  }
  __syncthreads();

  const f32x4 vzero = {0.f, 0.f, 0.f, 0.f};
  bf16_t* pw = &pb[wave][0];

  for (int ch = wave; ch < 13; ch += 4) {
    const int q0 = ch * 16;
    int qrow = q0 + l16;
    if (qrow > 195) qrow = 195;  // clamp; junk rows never stored
    const bf16x8 aq = *(const bf16x8*)(qg + qrow * 32 + quad * 8);

    // prefetch bias into registers (independent of the MFMAs below)
    float bv[13][4];
#pragma unroll
    for (int ct = 0; ct < 13; ++ct) {
      const int col = ct * 16 + l16;
#pragma unroll
      for (int r = 0; r < 4; ++r) {
        int br = q0 + quad * 4 + r;
        if (br > 195) br = 195;
        bv[ct][r] = (col < 196) ? bg[br * 196 + col] : 0.f;
      }
    }

    f32x4 s[13];
#pragma unroll
    for (int ct = 0; ct < 13; ++ct) {
      const bf16x8 bk = *(const bf16x8*)(kf + (ct * 16 + l16) * KSTR + quad * 8);
      s[ct] = __builtin_amdgcn_mfma_f32_16x16x32_bf16(aq, bk, vzero, 0, 0, 0);
    }
#pragma unroll
    for (int ct = 0; ct < 13; ++ct) {
      const int col = ct * 16 + l16;
#pragma unroll
      for (int r = 0; r < 4; ++r) {
        if (col < 196)
          s[ct][r] += bv[ct][r];
        else
          s[ct][r] = -1e30f;
      }
    }
    // row max (cols of one row live in the 16-lane group)
    float mx[4], inv[4];
#pragma unroll
    for (int r = 0; r < 4; ++r) {
      float m = s[0][r];
#pragma unroll
      for (int ct = 1; ct < 13; ++ct) m = fmaxf(m, s[ct][r]);
      m = fmaxf(m, __shfl_xor(m, 1));
      m = fmaxf(m, __shfl_xor(m, 2));
      m = fmaxf(m, __shfl_xor(m, 4));
      m = fmaxf(m, __shfl_xor(m, 8));
      mx[r] = m;
    }
#pragma unroll
    for (int ct = 0; ct < 13; ++ct)
#pragma unroll
      for (int r = 0; r < 4; ++r) s[ct][r] = __expf(s[ct][r] - mx[r]);  // masked -> 0
#pragma unroll
    for (int r = 0; r < 4; ++r) {
      float sum = s[0][r];
#pragma unroll
      for (int ct = 1; ct < 13; ++ct) sum += s[ct][r];
      sum += __shfl_xor(sum, 1);
      sum += __shfl_xor(sum, 2);
      sum += __shfl_xor(sum, 4);
      sum += __shfl_xor(sum, 8);
      inv[r] = 1.f / sum;
    }
    // P -> wave-private LDS (C layout -> memory [row][col])
#pragma unroll
    for (int ct = 0; ct < 13; ++ct) {
      const int col = ct * 16 + l16;
#pragma unroll
      for (int r = 0; r < 4; ++r) pw[(quad * 4 + r) * VSTR + col] = (bf16_t)s[ct][r];
    }
    // zero pad tile (cols 208..223)
    if (lane < 32) {
      const bf16x8 z8 = {};
      *(bf16x8*)(pw + (lane >> 1) * VSTR + 208 + (lane & 1) * 8) = z8;
    }
    // PV: same-wave LDS read-back (A layout), no barrier needed
#pragma unroll
    for (int dt = 0; dt < 2; ++dt) {
      f32x4 o = vzero;
#pragma unroll
      for (int kk = 0; kk < 7; ++kk) {
        const bf16x8 ap = *(const bf16x8*)(pw + l16 * VSTR + kk * 32 + quad * 8);
        const bf16x8 bv2 = *(const bf16x8*)(vts + (dt * 16 + l16) * VSTR + kk * 32 + quad * 8);
        o = __builtin_amdgcn_mfma_f32_16x16x32_bf16(ap, bv2, o, 0, 0, 0);
      }
      const int d = dt * 16 + l16;
#pragma unroll
      for (int r = 0; r < 4; ++r) {
        const int n = q0 + quad * 4 + r;
        if (n < 196)
          attn_out[(((size_t)b * 196 + n) * 32 + h) * 32 + d] = (bf16_t)(o[r] * inv[r]);
      }
    }
  }
}

extern "C" void kernel_launch(void* const* d_in, const int* in_sizes, int n_in,
                              void* d_out, int out_size, void* d_ws, size_t ws_size,
                              hipStream_t stream) {
  (void)in_sizes; (void)n_in; (void)out_size; (void)ws_size;
  const float* x = (const float*)d_in[0];
  const float* Wqkv = (const float*)d_in[1];
  const float* Wproj = (const float*)d_in[2];
  const float* bproj = (const float*)d_in[3];
  const float* rpk = (const float*)d_in[4];
  const int* rel_idx = (const int*)d_in[5];
  float* out = (float*)d_out;

  char* ws = (char*)d_ws;
  bf16_t* xb = (bf16_t*)(ws + 0);                  // 25,690,112 B ; reused as attn_out
  bf16_t* wqkvT = (bf16_t*)(ws + 25690112);        //  6,291,456 B
  bf16_t* wprojT = (bf16_t*)(ws + 31981568);       //  2,097,152 B
  bf16_t* q = (bf16_t*)(ws + 34078720);            // 25,690,112 B
  bf16_t* kk = (bf16_t*)(ws + 59768832);           // 25,690,112 B
  bf16_t* vt = (bf16_t*)(ws + 85458944);           // 25,690,112 B
  float* bias = (float*)(ws + 111149056);          //  4,917,248 B  (total ~116 MB)
  bf16_t* attn = xb;                               // xb is dead after GEMM1

  cast_x_kernel<<<12544, 256, 0, stream>>>(x, xb, 12845056 / 4);
  transpose_cast_kernel<<<dim3(96, 32), 256, 0, stream>>>(Wqkv, wqkvT, 1024, 3072);
  transpose_cast_kernel<<<dim3(32, 32), 256, 0, stream>>>(Wproj, wprojT, 1024, 1024);
  bias_gather_kernel<<<151, 256, 0, stream>>>(rpk, rel_idx, bias);
  gemm_bt_kernel<0><<<dim3(24, 49), 512, 0, stream>>>(xb, wqkvT, q, kk, vt, nullptr, nullptr);
  attn_kernel<<<2048, 256, 0, stream>>>(q, kk, vt, bias, attn);
  gemm_bt_kernel<1><<<dim3(8, 49), 512, 0, stream>>>(attn, wprojT, nullptr, nullptr, nullptr, out, bproj);
}

// Round 8
// 341.831 us; speedup vs baseline: 1.0826x; 1.0092x over previous
//
#include <hip/hip_runtime.h>
#include <hip/hip_bf16.h>

typedef __bf16 bf16_t;
typedef __attribute__((ext_vector_type(8))) __bf16 bf16x8;
typedef __attribute__((ext_vector_type(4))) __bf16 bf16x4;
typedef __attribute__((ext_vector_type(4))) float f32x4;

#define NPOS 38416  // 196*196
#define NPAD 224    // 7*32
#define KSTR 40     // kf row stride (bf16): 80B = 20 banks -> 2-way (free)
#define VSTR 232    // vts/pb row stride (bf16): 464B, 16B-aligned, 2-way

__device__ __forceinline__ void async_copy16(const bf16_t* g, bf16_t* l) {
  __builtin_amdgcn_global_load_lds((const __attribute__((address_space(1))) void*)g,
                                   (__attribute__((address_space(3))) void*)l, 16, 0, 0);
}

// ---------------- cast x -> bf16 ----------------
__global__ __launch_bounds__(256) void cast_x_kernel(const float* __restrict__ x,
                                                     bf16_t* __restrict__ xb, int n4) {
  int i = blockIdx.x * 256 + threadIdx.x;
  if (i < n4) {
    float4 v = ((const float4*)x)[i];
    bf16x4 o;
    o[0] = (bf16_t)v.x; o[1] = (bf16_t)v.y; o[2] = (bf16_t)v.z; o[3] = (bf16_t)v.w;
    ((bf16x4*)xb)[i] = o;
  }
}

// ---------------- transpose + cast W: src[K][Ncols] f32 -> dst[Ncols][K] bf16 ----------------
__global__ __launch_bounds__(256) void transpose_cast_kernel(const float* __restrict__ src,
                                                             bf16_t* __restrict__ dst,
                                                             int K, int Ncols) {
  __shared__ float tile[32][33];
  int t = threadIdx.x;
  int tx = t & 31, ty = t >> 5;
  int bx = blockIdx.x, by = blockIdx.y;
  for (int r = ty; r < 32; r += 8)
    tile[r][tx] = src[(size_t)(by * 32 + r) * Ncols + bx * 32 + tx];
  __syncthreads();
  for (int r = ty; r < 32; r += 8)
    dst[(size_t)(bx * 32 + r) * K + by * 32 + tx] = (bf16_t)tile[tx][r];
}

// ---------------- bias gather: bias[h][i*196+j] = rpk[rel_idx[i][j]][h] ----------------
__global__ __launch_bounds__(256) void bias_gather_kernel(const float* __restrict__ rpk,
                                                          const int* __restrict__ rel_idx,
                                                          float* __restrict__ bias) {
  int pos = blockIdx.x * 256 + threadIdx.x;
  if (pos < NPOS) {
    int idx = rel_idx[pos];
    const float* r = rpk + idx * 32;
#pragma unroll
    for (int h = 0; h < 32; ++h) bias[h * NPOS + pos] = r[h];
  }
}

// ---------------- 256x128 bf16 GEMM, B^T input, K=1024 ----------------
// PROVEN round-3 structure (119.8 us gemm1, 342.9 total): 512 threads /
// 8 waves (4x2 of 64x64). Double-buffered LDS (48 KiB -> 3 blocks/CU;
// cross-block overlap hides the barrier drain), ONE barrier per K-iter.
// 16B-chunk XOR swizzle (phys_chunk = glob_chunk ^ ((row>>1)&3)).
// Bijective XCD-chunked block swizzle (FETCH -22% measured, time-neutral,
// kept for headroom).  Do NOT retile to 128^2 (r4: FETCH doubles, +13 us).
template <int MODE>
__global__ __launch_bounds__(512, 4) void gemm_bt_kernel(
    const bf16_t* __restrict__ A, const bf16_t* __restrict__ Bt,
    bf16_t* __restrict__ qo, bf16_t* __restrict__ ko, bf16_t* __restrict__ vto,
    float* __restrict__ fo, const float* __restrict__ bp) {
  constexpr int K = 1024;
  constexpr int CH = 384 * 32;  // bf16 elems per buffer: (256 A-rows + 128 B-rows) x 32
  __shared__ alignas(16) bf16_t S[2][CH];
  const int t = threadIdx.x;
  const int lane = t & 63;
  const int quad = lane >> 4;
  const int l16 = lane & 15;
  const int wave = t >> 6;

  // T1: bijective XCD-chunked swizzle (m204)
  const int GX = gridDim.x;
  const int nwg = GX * gridDim.y;
  const int lin = blockIdx.y * GX + blockIdx.x;
  const int qch = nwg >> 3, rch = nwg & 7;
  const int xcd = lin & 7, off = lin >> 3;
  const int swz = (xcd < rch ? xcd * (qch + 1) : rch * (qch + 1) + (xcd - rch) * qch) + off;
  const int m0 = (swz / GX) * 256, n0 = (swz % GX) * 128;

  const int wr = (wave >> 1) * 64, wc = (wave & 1) * 64;

  // staging: 1536 16B-chunks; thread t covers c = t, t+512, t+1024
  const bf16_t* gp[3];
  int lofs[3];
#pragma unroll
  for (int j = 0; j < 3; ++j) {
    const int c = t + j * 512;
    const int row = c >> 2;
    const int sc = (c & 3) ^ ((c >> 3) & 3);
    gp[j] = (row < 256) ? A + (size_t)(m0 + row) * K + sc * 8
                        : Bt + (size_t)(n0 + row - 256) * K + sc * 8;
    lofs[j] = c * 8;
  }

  // fragment reads: global chunk `quad` lives at phys chunk quad ^ ((l16>>1)&3)
  const int qa = quad ^ ((l16 >> 1) & 3);

  const f32x4 vzero = {0.f, 0.f, 0.f, 0.f};
  f32x4 acc[4][4];
#pragma unroll
  for (int i = 0; i < 4; ++i)
#pragma unroll
    for (int j = 0; j < 4; ++j) acc[i][j] = vzero;

  // preload k-tile 0 into S[0]
#pragma unroll
  for (int j = 0; j < 3; ++j) async_copy16(gp[j], &S[0][lofs[j]]);

  for (int it = 0; it < K / 32; ++it) {
    __syncthreads();  // drains loads issued one full iteration ago
    const bf16_t* Sb = S[it & 1];
    if (it + 1 < K / 32) {
      bf16_t* Sn = S[(it + 1) & 1];
      const int kt = (it + 1) * 32;
#pragma unroll
      for (int j = 0; j < 3; ++j) async_copy16(gp[j] + kt, Sn + lofs[j]);
    }
    const bf16_t* As = Sb;
    const bf16_t* Bs = Sb + 256 * 32;
    bf16x8 af[4], bfr[4];
#pragma unroll
    for (int i = 0; i < 4; ++i) {
      af[i] = *(const bf16x8*)(As + (wr + i * 16 + l16) * 32 + qa * 8);
      bfr[i] = *(const bf16x8*)(Bs + (wc + i * 16 + l16) * 32 + qa * 8);
    }
#pragma unroll
    for (int i = 0; i < 4; ++i)
#pragma unroll
      for (int j = 0; j < 4; ++j)
        acc[i][j] = __builtin_amdgcn_mfma_f32_16x16x32_bf16(af[i], bfr[j], acc[i][j], 0, 0, 0);
  }

  if (MODE == 0) {
    const float qscale = 0.17677669529663687f;  // 1/sqrt(32)
    const int which = n0 >> 10;                 // uniform per block (1024 % 128 == 0)
#pragma unroll
    for (int i = 0; i < 4; ++i) {
      const int rb = m0 + wr + i * 16 + quad * 4;
#pragma unroll
      for (int j = 0; j < 4; ++j) {
        const int c = n0 + wc + j * 16 + l16;
        const int h = (c >> 5) & 31, d = c & 31;
#pragma unroll
        for (int r = 0; r < 4; ++r) {
          const int rg = rb + r;
          const int b = rg / 196, n = rg - b * 196;
          const float v = acc[i][j][r];
          if (which == 0)
            qo[(((size_t)b * 32 + h) * 196 + n) * 32 + d] = (bf16_t)(v * qscale);
          else if (which == 1)
            ko[(((size_t)b * 32 + h) * 196 + n) * 32 + d] = (bf16_t)v;
          else
            vto[(((size_t)b * 32 + h) * 32 + d) * 196 + n] = (bf16_t)v;
        }
      }
    }
  } else {
#pragma unroll
    for (int i = 0; i < 4; ++i) {
      const int rb = m0 + wr + i * 16 + quad * 4;
#pragma unroll
      for (int j = 0; j < 4; ++j) {
        const int c = n0 + wc + j * 16 + l16;
        const float bias_c = bp[c];
#pragma unroll
        for (int r = 0; r < 4; ++r)
          fo[(size_t)(rb + r) * 1024 + c] = acc[i][j][r] + bias_c;
      }
    }
  }
}

// ---------------- attention: one block per (b,h) ----------------
// r8 package (attn-internal only): (1) T14 bias software-pipeline — chunk
// i+1's 52 bias loads issue before chunk i's PV, hiding L2 latency under
// PV+next-QK; chunk 0's loads issue before the staging barrier (land free).
// Ping-pong register buffers bvA/bvB with explicit 4x unroll (static
// indexing).  (2) T5 setprio around QK and PV MFMA clusters (+4-7% attn,
// m191).  (3) Tree max/sum reductions (dep chain 12 -> 4).
#define LOADB(Q0, BV)                                                         \
  _Pragma("unroll") for (int ct = 0; ct < 13; ++ct) {                         \
    const int col = ct * 16 + l16;                                            \
    _Pragma("unroll") for (int r = 0; r < 4; ++r) {                           \
      int br = (Q0) + quad * 4 + r;                                           \
      if (br > 195) br = 195;                                                 \
      BV[ct][r] = (col < 196) ? bg[br * 196 + col] : 0.f;                     \
    }                                                                         \
  }

#define AITER(Q0, BVC, QN, BVN, PREF)                                         \
  {                                                                           \
    const int q0_ = (Q0);                                                     \
    int qrow_ = q0_ + l16;                                                    \
    if (qrow_ > 195) qrow_ = 195;                                             \
    const bf16x8 aq_ = *(const bf16x8*)(qg + qrow_ * 32 + quad * 8);          \
    f32x4 s[13];                                                              \
    __builtin_amdgcn_s_setprio(1);                                            \
    _Pragma("unroll") for (int ct = 0; ct < 13; ++ct) {                       \
      const bf16x8 bk_ = *(const bf16x8*)(kf + (ct * 16 + l16) * KSTR + quad * 8); \
      s[ct] = __builtin_amdgcn_mfma_f32_16x16x32_bf16(aq_, bk_, vzero, 0, 0, 0); \
    }                                                                         \
    __builtin_amdgcn_s_setprio(0);                                            \
    _Pragma("unroll") for (int ct = 0; ct < 13; ++ct) {                       \
      const int col = ct * 16 + l16;                                          \
      _Pragma("unroll") for (int r = 0; r < 4; ++r) {                         \
        if (col < 196) s[ct][r] += BVC[ct][r];                                \
        else s[ct][r] = -1e30f;                                               \
      }                                                                       \
    }                                                                         \
    float mx[4], inv[4];                                                      \
    _Pragma("unroll") for (int r = 0; r < 4; ++r) {                           \
      float p0_ = fmaxf(s[0][r], s[1][r]), p1_ = fmaxf(s[2][r], s[3][r]);     \
      float p2_ = fmaxf(s[4][r], s[5][r]), p3_ = fmaxf(s[6][r], s[7][r]);     \
      float p4_ = fmaxf(s[8][r], s[9][r]), p5_ = fmaxf(s[10][r], s[11][r]);   \
      float m_ = fmaxf(fmaxf(fmaxf(p0_, p1_), fmaxf(p2_, p3_)),               \
                       fmaxf(fmaxf(p4_, p5_), s[12][r]));                     \
      m_ = fmaxf(m_, __shfl_xor(m_, 1));                                      \
      m_ = fmaxf(m_, __shfl_xor(m_, 2));                                      \
      m_ = fmaxf(m_, __shfl_xor(m_, 4));                                      \
      m_ = fmaxf(m_, __shfl_xor(m_, 8));                                      \
      mx[r] = m_;                                                             \
    }                                                                         \
    _Pragma("unroll") for (int ct = 0; ct < 13; ++ct)                         \
      _Pragma("unroll") for (int r = 0; r < 4; ++r)                           \
        s[ct][r] = __expf(s[ct][r] - mx[r]);                                  \
    _Pragma("unroll") for (int r = 0; r < 4; ++r) {                           \
      float a0_ = (s[0][r] + s[1][r]) + (s[2][r] + s[3][r]);                  \
      float a1_ = (s[4][r] + s[5][r]) + (s[6][r] + s[7][r]);                  \
      float a2_ = (s[8][r] + s[9][r]) + (s[10][r] + s[11][r]);                \
      float sum_ = a0_ + a1_ + (a2_ + s[12][r]);                              \
      sum_ += __shfl_xor(sum_, 1);                                            \
      sum_ += __shfl_xor(sum_, 2);                                            \
      sum_ += __shfl_xor(sum_, 4);                                            \
      sum_ += __shfl_xor(sum_, 8);                                            \
      inv[r] = 1.f / sum_;                                                    \
    }                                                                         \
    _Pragma("unroll") for (int ct = 0; ct < 13; ++ct) {                       \
      const int col = ct * 16 + l16;                                          \
      _Pragma("unroll") for (int r = 0; r < 4; ++r)                           \
        pw[(quad * 4 + r) * VSTR + col] = (bf16_t)s[ct][r];                   \
    }                                                                         \
    if (lane < 32) {                                                          \
      const bf16x8 z8_ = {};                                                  \
      *(bf16x8*)(pw + (lane >> 1) * VSTR + 208 + (lane & 1) * 8) = z8_;       \
    }                                                                         \
    if (PREF) { LOADB((QN), BVN); }                                           \
    _Pragma("unroll") for (int dt = 0; dt < 2; ++dt) {                        \
      f32x4 o_ = vzero;                                                       \
      __builtin_amdgcn_s_setprio(1);                                          \
      _Pragma("unroll") for (int kk2 = 0; kk2 < 7; ++kk2) {                   \
        const bf16x8 ap_ = *(const bf16x8*)(pw + l16 * VSTR + kk2 * 32 + quad * 8); \
        const bf16x8 bv2_ = *(const bf16x8*)(vts + (dt * 16 + l16) * VSTR + kk2 * 32 + quad * 8); \
        o_ = __builtin_amdgcn_mfma_f32_16x16x32_bf16(ap_, bv2_, o_, 0, 0, 0); \
      }                                                                       \
      __builtin_amdgcn_s_setprio(0);                                          \
      const int d_ = dt * 16 + l16;                                           \
      _Pragma("unroll") for (int r = 0; r < 4; ++r) {                         \
        const int n_ = q0_ + quad * 4 + r;                                    \
        if (n_ < 196)                                                         \
          attn_out[(((size_t)b * 196 + n_) * 32 + h) * 32 + d_] =             \
              (bf16_t)(o_[r] * inv[r]);                                       \
      }                                                                       \
    }                                                                         \
  }

__global__ __launch_bounds__(256, 2) void attn_kernel(
    const bf16_t* __restrict__ q, const bf16_t* __restrict__ kmat,
    const bf16_t* __restrict__ vtg, const float* __restrict__ bias,
    bf16_t* __restrict__ attn_out) {
  __shared__ alignas(16) bf16_t kf[NPAD * KSTR];    // K rows [n][d], stride 40
  __shared__ alignas(16) bf16_t vts[32 * VSTR];     // V^T [d][n], stride 232
  __shared__ alignas(16) bf16_t pb[4][16 * VSTR];   // per-wave unnormalized P

  const int t = threadIdx.x;
  const int lane = t & 63;
  const int quad = lane >> 4, l16 = lane & 15;
  const int wave = t >> 6;
  const int bh = blockIdx.x;                        // b-major (r3 config)
  const int b = bh >> 5, h = bh & 31;
  const bf16_t* qg = q + (size_t)bh * (196 * 32);
  const bf16_t* kg = kmat + (size_t)bh * (196 * 32);
  const bf16_t* vg = vtg + (size_t)bh * (32 * 196);
  const float* bg = bias + (size_t)h * NPOS;

  // issue chunk-0 bias loads BEFORE staging: the staging barrier's vmcnt(0)
  // drain guarantees they have landed by loop start, at zero exposed latency.
  float bvA[13][4], bvB[13][4];
  LOADB(wave * 16, bvA);

  {
    const uint4* src = (const uint4*)kg;
    uint4* dst = (uint4*)kf;  // row r -> uint4 slots [r*5, r*5+3]; slot r*5+4 unused
    for (int c = t; c < 784; c += 256) dst[(c >> 2) * 5 + (c & 3)] = src[c];
    const uint4 z4 = {0u, 0u, 0u, 0u};
    if (t < 112) {  // zero pad rows 196..223, chunks 0..3
      int r = 196 + (t >> 2), ch = t & 3;
      dst[r * 5 + ch] = z4;
    }
    const uint2 z2 = {0u, 0u};
    for (int i = t; i < 1792; i += 256) {  // 32 rows x 56 x 8B (stride VSTR)
      int d = i / 56, c = i - d * 56;
      uint2 val = (c < 49) ? ((const uint2*)(vg + d * 196))[c] : z2;
      ((uint2*)(vts + d * VSTR))[c] = val;
    }
  }
  __syncthreads();

  const f32x4 vzero = {0.f, 0.f, 0.f, 0.f};
  bf16_t* pw = &pb[wave][0];

  // chunks ch = wave, wave+4, wave+8, wave+12 (<13); explicit unroll with
  // ping-pong bias buffers (static register indexing, rule #20)
  AITER(wave * 16, bvA, (wave + 4) * 16, bvB, true);
  AITER((wave + 4) * 16, bvB, (wave + 8) * 16, bvA, true);
  AITER((wave + 8) * 16, bvA, (wave + 12) * 16, bvB, (wave + 12 < 13));
  if (wave + 12 < 13)
    AITER((wave + 12) * 16, bvB, 0, bvA, false);
}

extern "C" void kernel_launch(void* const* d_in, const int* in_sizes, int n_in,
                              void* d_out, int out_size, void* d_ws, size_t ws_size,
                              hipStream_t stream) {
  (void)in_sizes; (void)n_in; (void)out_size; (void)ws_size;
  const float* x = (const float*)d_in[0];
  const float* Wqkv = (const float*)d_in[1];
  const float* Wproj = (const float*)d_in[2];
  const float* bproj = (const float*)d_in[3];
  const float* rpk = (const float*)d_in[4];
  const int* rel_idx = (const int*)d_in[5];
  float* out = (float*)d_out;

  char* ws = (char*)d_ws;
  bf16_t* xb = (bf16_t*)(ws + 0);                  // 25,690,112 B ; reused as attn_out
  bf16_t* wqkvT = (bf16_t*)(ws + 25690112);        //  6,291,456 B
  bf16_t* wprojT = (bf16_t*)(ws + 31981568);       //  2,097,152 B
  bf16_t* q = (bf16_t*)(ws + 34078720);            // 25,690,112 B
  bf16_t* kk = (bf16_t*)(ws + 59768832);           // 25,690,112 B
  bf16_t* vt = (bf16_t*)(ws + 85458944);           // 25,690,112 B
  float* bias = (float*)(ws + 111149056);          //  4,917,248 B  (total ~116 MB)
  bf16_t* attn = xb;                               // xb is dead after GEMM1

  cast_x_kernel<<<12544, 256, 0, stream>>>(x, xb, 12845056 / 4);
  transpose_cast_kernel<<<dim3(96, 32), 256, 0, stream>>>(Wqkv, wqkvT, 1024, 3072);
  transpose_cast_kernel<<<dim3(32, 32), 256, 0, stream>>>(Wproj, wprojT, 1024, 1024);
  bias_gather_kernel<<<151, 256, 0, stream>>>(rpk, rel_idx, bias);
  gemm_bt_kernel<0><<<dim3(24, 49), 512, 0, stream>>>(xb, wqkvT, q, kk, vt, nullptr, nullptr);
  attn_kernel<<<2048, 256, 0, stream>>>(q, kk, vt, bias, attn);
  gemm_bt_kernel<1><<<dim3(8, 49), 512, 0, stream>>>(attn, wprojT, nullptr, nullptr, nullptr, out, bproj);
}